// Round 7
// baseline (48.117 us; speedup 1.0000x reference)
//
#include <hip/hip_runtime.h>
#include <math.h>

#define D_DIM 128
#define M_CLUSTERS 64
#define TILE_ROWS 64      // rows per tile = 4 waves x 16 rows
#define TPB 4             // tiles per block
#define BLOCK 256
#define RBLOCK 256

typedef __bf16 bf16x8 __attribute__((ext_vector_type(8)));
typedef float f32x4 __attribute__((ext_vector_type(4)));

union B8 {
    int4 i;
    bf16x8 b;
};

__device__ __forceinline__ float zval(float sq) {
    float dd = sqrtf(fmaxf(sq, 0.0f));
    float sg = __fdividef(1.0f, 1.0f + __expf(dd));
    return -__logf(sg + 1e-8f);
}

// Async global->LDS, 16B per lane: lds dest = base + lane*16 (HW rule).
__device__ __forceinline__ void gload16(const void* g, void* l) {
    __builtin_amdgcn_global_load_lds(
        (const __attribute__((address_space(1))) unsigned int*)g,
        (__attribute__((address_space(3))) unsigned int*)l, 16, 0, 0);
}

// Prep (grid=4): muB4 = bf16(mus) [64 clusters][16 slots of 16B]; m2 = ||mu||^2.
__global__ void iso_prep(const float4* __restrict__ mus4, int4* __restrict__ muB4,
                         float* __restrict__ m2) {
    const int f = blockIdx.x * 256 + threadIdx.x;   // 1024 chunks of 8 f32
    float4 v0 = mus4[f * 2 + 0];
    float4 v1 = mus4[f * 2 + 1];
    B8 p;
    p.b[0] = (__bf16)v0.x; p.b[1] = (__bf16)v0.y;
    p.b[2] = (__bf16)v0.z; p.b[3] = (__bf16)v0.w;
    p.b[4] = (__bf16)v1.x; p.b[5] = (__bf16)v1.y;
    p.b[6] = (__bf16)v1.z; p.b[7] = (__bf16)v1.w;
    muB4[f] = p.i;
    if (blockIdx.x == 0 && threadIdx.x < M_CLUSTERS) {
        const float4* mv = mus4 + threadIdx.x * (D_DIM / 4);
        float s = 0.f;
#pragma unroll
        for (int d = 0; d < D_DIM / 4; ++d) {
            float4 v = mv[d];
            s = fmaf(v.x, v.x, s);
            s = fmaf(v.y, v.y, s);
            s = fmaf(v.z, v.z, s);
            s = fmaf(v.w, v.w, s);
        }
        m2[threadIdx.x] = s;
    }
}

// Main: per-block 4-tile software pipeline, wave-private X buffers, no loop
// barriers. DMA(t+1) overlaps epilogue(t); r(t) loads overlap K-loop(t).
__global__ __launch_bounds__(BLOCK, 4) void iso_main(
        const float* __restrict__ X, const float* __restrict__ r,
        const int4* __restrict__ muB4, const float* __restrict__ m2g,
        float* __restrict__ partials, int N) {
    __shared__ __align__(16) char xs_raw[4 * 8192];   // 32 KB: wave-private X
    __shared__ __align__(16) char bs_raw[16384];      // 16 KB: mus bf16 (shared)
    __shared__ float pl[BLOCK];

    const int tid = threadIdx.x;
    const int lane = tid & 63;
    const int la = lane & 15;
    const int lg = lane >> 4;
    const int w = tid >> 6;

    char* xw = xs_raw + w * 8192;
    char* bs = bs_raw;

    const int rr = (lane >> 5);            // X-staging: row parity within chunk
    const int xslot = (lane & 31);         // X-staging: lane's 16B slot

    // ---- Prologue ----
    // mus DMA: wave w stages chunks w*4..w*4+3 (4 clusters of 256B each).
#pragma unroll
    for (int i = 0; i < 4; ++i) {
        int k = w * 4 + i;
        int c = k * 4 + (lane >> 4);
        int slot = (lane & 15) ^ (c & 7);
        gload16(muB4 + c * 16 + slot, bs + k * 1024);
    }
    // X DMA for tile 0 (wave's 16 rows, 8 chunks of 2 rows).
    {
        int rowbase = blockIdx.x * (TPB * TILE_ROWS) + w * 16;
#pragma unroll
        for (int c = 0; c < 8; ++c) {
            int row = c * 2 + rr;
            int grow = rowbase + row;
            grow = grow < N ? grow : N - 1;
            int slot = xslot ^ (row & 7);
            gload16(X + (size_t)grow * D_DIM + slot * 4, xw + c * 1024);
        }
    }
    float m2r[4];
#pragma unroll
    for (int cb = 0; cb < 4; ++cb) m2r[cb] = m2g[cb * 16 + la];
    __syncthreads();   // drains vmcnt(0); bs now valid for all waves

    float partial = 0.f;

    for (int t = 0; t < TPB; ++t) {
        const int rowbase = (blockIdx.x * TPB + t) * TILE_ROWS + w * 16;

        // r loads for tile t (overlap the K-loop below).
        float rv[4][4];
        const int erow = rowbase + lg * 4;
#pragma unroll
        for (int q = 0; q < 4; ++q) {
            int rrow = erow + q;
            const float* rr_ =
                r + (size_t)(rrow < N ? rrow : N - 1) * M_CLUSTERS + la;
#pragma unroll
            for (int cb = 0; cb < 4; ++cb)
                rv[q][cb] = (rrow < N) ? rr_[cb * 16] : 0.f;
        }

        // Drain only DMA(t): allow the 16 r loads to stay in flight.
        asm volatile("s_waitcnt vmcnt(16)" ::: "memory");
        __builtin_amdgcn_sched_barrier(0);

        // K-loop from LDS.
        f32x4 acc[4];
#pragma unroll
        for (int cb = 0; cb < 4; ++cb)
#pragma unroll
            for (int q = 0; q < 4; ++q) acc[cb][q] = 0.f;
        float x2 = 0.f;

#pragma unroll
        for (int kk = 0; kk < 4; ++kk) {
            int s0 = kk * 8 + lg * 2;
            float4 xa = *(const float4*)(xw + la * 512 + ((s0) ^ (la & 7)) * 16);
            float4 xb = *(const float4*)(xw + la * 512 + ((s0 + 1) ^ (la & 7)) * 16);
            B8 a;
            a.b[0] = (__bf16)xa.x; a.b[1] = (__bf16)xa.y;
            a.b[2] = (__bf16)xa.z; a.b[3] = (__bf16)xa.w;
            a.b[4] = (__bf16)xb.x; a.b[5] = (__bf16)xb.y;
            a.b[6] = (__bf16)xb.z; a.b[7] = (__bf16)xb.w;
            x2 = fmaf(xa.x, xa.x, x2); x2 = fmaf(xa.y, xa.y, x2);
            x2 = fmaf(xa.z, xa.z, x2); x2 = fmaf(xa.w, xa.w, x2);
            x2 = fmaf(xb.x, xb.x, x2); x2 = fmaf(xb.y, xb.y, x2);
            x2 = fmaf(xb.z, xb.z, x2); x2 = fmaf(xb.w, xb.w, x2);
            B8 b[4];
#pragma unroll
            for (int cb = 0; cb < 4; ++cb) {
                int cc = cb * 16 + la;
                int tt = (kk * 4 + lg) ^ (cc & 7);
                b[cb].i = *(const int4*)(bs + cc * 256 + tt * 16);
            }
#pragma unroll
            for (int cb = 0; cb < 4; ++cb)
                acc[cb] = __builtin_amdgcn_mfma_f32_16x16x32_bf16(
                    a.b, b[cb].b, acc[cb], 0, 0, 0);
        }

        // X buffer free once all ds_reads retired -> prefetch tile t+1 into it.
        asm volatile("s_waitcnt lgkmcnt(0)" ::: "memory");
        __builtin_amdgcn_sched_barrier(0);
        {
            int nrowbase = rowbase + TILE_ROWS;   // next tile, same wave slot
#pragma unroll
            for (int c = 0; c < 8; ++c) {
                int row = c * 2 + rr;
                int grow = nrowbase + row;
                grow = grow < N ? grow : N - 1;
                int slot = xslot ^ (row & 7);
                gload16(X + (size_t)grow * D_DIM + slot * 4, xw + c * 1024);
            }
        }

        // x2: reduce quarter-sums over lg, fetch epilogue rows' values.
        x2 += __shfl_xor(x2, 16, 64);
        x2 += __shfl_xor(x2, 32, 64);
        float x2r[4];
#pragma unroll
        for (int q = 0; q < 4; ++q) x2r[q] = __shfl(x2, lg * 4 + q, 64);

        // Epilogue (compiler inserts counted vmcnt for rv; DMA keeps flying).
        // C/D layout col=la, row=lg*4+q (verified: absmax=0 rounds 3-6).
#pragma unroll
        for (int q = 0; q < 4; ++q)
#pragma unroll
            for (int cb = 0; cb < 4; ++cb) {
                float sq = x2r[q] + m2r[cb] - 2.0f * acc[cb][q];
                partial = fmaf(rv[q][cb], zval(sq), partial);
            }
    }

    // Block reduce (single barrier at end; drains the last dangling DMA too).
    pl[tid] = partial;
    __syncthreads();
    if (tid < 64) {
        float s = pl[lane] + pl[64 + lane] + pl[128 + lane] + pl[192 + lane];
#pragma unroll
        for (int off = 32; off > 0; off >>= 1)
            s += __shfl_down(s, off, 64);
        if (lane == 0) partials[blockIdx.x] = s;
    }
}

// Deterministic fixed-order final reduction.
__global__ void iso_reduce(const float* __restrict__ partials, int nblocks,
                           float* __restrict__ out, float invN) {
    float s = 0.f;
    for (int i = threadIdx.x; i < nblocks; i += RBLOCK) s += partials[i];
#pragma unroll
    for (int off = 32; off > 0; off >>= 1)
        s += __shfl_down(s, off, 64);
    __shared__ float wsum[RBLOCK / 64];
    const int lane = threadIdx.x & 63;
    const int wid = threadIdx.x >> 6;
    if (lane == 0) wsum[wid] = s;
    __syncthreads();
    if (threadIdx.x == 0)
        out[0] = (wsum[0] + wsum[1] + wsum[2] + wsum[3]) * invN;
}

extern "C" void kernel_launch(void* const* d_in, const int* in_sizes, int n_in,
                              void* d_out, int out_size, void* d_ws, size_t ws_size,
                              hipStream_t stream) {
    const float* X = (const float*)d_in[0];    // [N,128]
    const float* r = (const float*)d_in[1];    // [N,64]
    const float* mus = (const float*)d_in[2];  // [64,128]
    const int N = in_sizes[0] / D_DIM;

    // ws: muB4 (1024 int4 = 16KB) | m2 (64 f32) | partials (nblocks f32)
    int4* muB4 = (int4*)d_ws;
    float* m2 = (float*)((char*)d_ws + 16384);
    float* partials = m2 + M_CLUSTERS;

    const int ntiles = (N + TILE_ROWS - 1) / TILE_ROWS;
    const int nblocks = (ntiles + TPB - 1) / TPB;

    hipLaunchKernelGGL(iso_prep, dim3(4), dim3(256), 0, stream,
                       (const float4*)mus, muB4, m2);
    hipLaunchKernelGGL(iso_main, dim3(nblocks), dim3(BLOCK), 0, stream,
                       X, r, muB4, m2, partials, N);
    hipLaunchKernelGGL(iso_reduce, dim3(1), dim3(RBLOCK), 0, stream,
                       partials, nblocks, (float*)d_out, 1.0f / (float)N);
}

// Round 8
// 44.533 us; speedup vs baseline: 1.0805x; 1.0805x over previous
//
#include <hip/hip_runtime.h>
#include <math.h>

#define D_DIM 128
#define M_CLUSTERS 64
#define BLOCK 512                   // 8 waves per block
#define GRID 256                    // 1 block per CU, all resident
#define WPB 8
#define TOTAL_WAVES (GRID * WPB)    // 2048
#define RBLOCK 256

typedef __bf16 bf16x8 __attribute__((ext_vector_type(8)));
typedef float f32x4 __attribute__((ext_vector_type(4)));

union B8 {
    int4 i;
    bf16x8 b;
};

__device__ __forceinline__ float zval(float sq) {
    float dd = sqrtf(fmaxf(sq, 0.0f));
    float sg = __fdividef(1.0f, 1.0f + __expf(dd));
    return -__logf(sg + 1e-8f);
}

// Async global->LDS, 16B/lane: lds dest = base + lane*16 (HW rule).
__device__ __forceinline__ void gload16(const void* g, void* l) {
    __builtin_amdgcn_global_load_lds(
        (const __attribute__((address_space(1))) unsigned int*)g,
        (__attribute__((address_space(3))) unsigned int*)l, 16, 0, 0);
}

// Inline-asm loads: invisible to the compiler's waitcnt tracker, so OUR
// counted vmcnt discipline is the only wait discipline (exact bookkeeping).
#define LOADF(dst, ptr, OFF)                                        \
    asm volatile("global_load_dword %0, %1, off offset:" #OFF       \
                 : "=v"(dst) : "v"(ptr) : "memory")
#define LOADX4(dst, ptr, OFF)                                       \
    asm volatile("global_load_dwordx4 %0, %1, off offset:" #OFF     \
                 : "=v"(dst) : "v"(ptr) : "memory")
#define WAITVM(N_)                                                  \
    do {                                                            \
        asm volatile("s_waitcnt vmcnt(" #N_ ")" ::: "memory");      \
        __builtin_amdgcn_sched_barrier(0);                          \
    } while (0)

// Prep (grid=4): muB4 = bf16(mus) [64 clusters][16 slots of 16B]; m2 = ||mu||^2.
__global__ void iso_prep(const float4* __restrict__ mus4, int4* __restrict__ muB4,
                         float* __restrict__ m2) {
    const int f = blockIdx.x * 256 + threadIdx.x;   // 1024 chunks of 8 f32
    float4 v0 = mus4[f * 2 + 0];
    float4 v1 = mus4[f * 2 + 1];
    B8 p;
    p.b[0] = (__bf16)v0.x; p.b[1] = (__bf16)v0.y;
    p.b[2] = (__bf16)v0.z; p.b[3] = (__bf16)v0.w;
    p.b[4] = (__bf16)v1.x; p.b[5] = (__bf16)v1.y;
    p.b[6] = (__bf16)v1.z; p.b[7] = (__bf16)v1.w;
    muB4[f] = p.i;
    if (blockIdx.x == 0 && threadIdx.x < M_CLUSTERS) {
        const float4* mv = mus4 + threadIdx.x * (D_DIM / 4);
        float s = 0.f;
#pragma unroll
        for (int d = 0; d < D_DIM / 4; ++d) {
            float4 v = mv[d];
            s = fmaf(v.x, v.x, s);
            s = fmaf(v.y, v.y, s);
            s = fmaf(v.z, v.z, s);
            s = fmaf(v.w, v.w, s);
        }
        m2[threadIdx.x] = s;
    }
}

__device__ __forceinline__ void load_rv(const float* rp, float (&rv)[4][4]) {
    LOADF(rv[0][0], rp, 0);   LOADF(rv[0][1], rp, 64);
    LOADF(rv[0][2], rp, 128); LOADF(rv[0][3], rp, 192);
    LOADF(rv[1][0], rp, 256); LOADF(rv[1][1], rp, 320);
    LOADF(rv[1][2], rp, 384); LOADF(rv[1][3], rp, 448);
    LOADF(rv[2][0], rp, 512); LOADF(rv[2][1], rp, 576);
    LOADF(rv[2][2], rp, 640); LOADF(rv[2][3], rp, 704);
    LOADF(rv[3][0], rp, 768); LOADF(rv[3][1], rp, 832);
    LOADF(rv[3][2], rp, 896); LOADF(rv[3][3], rp, 960);
}

// K-loop + epilogue for one 16-row tile. VMEPI = vmcnt level that drains the
// r-loads for this tile (8 in steady state: DMA(t+1) stays in flight; 0 at end).
template <int VMEPI>
__device__ __forceinline__ float compute_tile(
        const char* cur, int la, int lg,
        const B8 (&bfr)[4][4], const float (&m2r)[4], const float (&rv)[4][4]) {
    f32x4 acc[4];
#pragma unroll
    for (int cb = 0; cb < 4; ++cb)
#pragma unroll
        for (int q = 0; q < 4; ++q) acc[cb][q] = 0.f;
    float x2 = 0.f;

    const char* xrow = cur + la * 512;
    const int sw = la & 7;
#pragma unroll
    for (int kk = 0; kk < 4; ++kk) {
        int s0 = kk * 8 + lg * 2;
        float4 xa = *(const float4*)(xrow + ((s0) ^ sw) * 16);
        float4 xb = *(const float4*)(xrow + ((s0 + 1) ^ sw) * 16);
        B8 a;
        a.b[0] = (__bf16)xa.x; a.b[1] = (__bf16)xa.y;
        a.b[2] = (__bf16)xa.z; a.b[3] = (__bf16)xa.w;
        a.b[4] = (__bf16)xb.x; a.b[5] = (__bf16)xb.y;
        a.b[6] = (__bf16)xb.z; a.b[7] = (__bf16)xb.w;
        x2 = fmaf(xa.x, xa.x, x2); x2 = fmaf(xa.y, xa.y, x2);
        x2 = fmaf(xa.z, xa.z, x2); x2 = fmaf(xa.w, xa.w, x2);
        x2 = fmaf(xb.x, xb.x, x2); x2 = fmaf(xb.y, xb.y, x2);
        x2 = fmaf(xb.z, xb.z, x2); x2 = fmaf(xb.w, xb.w, x2);
#pragma unroll
        for (int cb = 0; cb < 4; ++cb)
            acc[cb] = __builtin_amdgcn_mfma_f32_16x16x32_bf16(
                a.b, bfr[cb][kk].b, acc[cb], 0, 0, 0);
    }

    // x2: lane (la,lg) holds quarter of row la -> reduce over lg; epilogue
    // rows lg*4+q fetch from lane index lg*4+q (whose la == that row).
    x2 += __shfl_xor(x2, 16, 64);
    x2 += __shfl_xor(x2, 32, 64);
    float x2r[4];
#pragma unroll
    for (int q = 0; q < 4; ++q) x2r[q] = __shfl(x2, lg * 4 + q, 64);

    if constexpr (VMEPI == 8) { WAITVM(8); } else { WAITVM(0); }

    // C/D layout col=la, row=lg*4+q (verified: absmax=0 rounds 3-7).
    float p = 0.f;
#pragma unroll
    for (int q = 0; q < 4; ++q)
#pragma unroll
        for (int cb = 0; cb < 4; ++cb) {
            float sq = x2r[q] + m2r[cb] - 2.0f * acc[cb][q];
            p = fmaf(rv[q][cb], zval(sq), p);
        }
    return p;
}

__global__ __launch_bounds__(BLOCK, 2) void iso_main(
        const float* __restrict__ X, const float* __restrict__ r,
        const int4* __restrict__ muB4, const float* __restrict__ m2g,
        float* __restrict__ partials, int N) {
    __shared__ __align__(16) char xs[WPB * 2 * 8192];   // 128 KB: per-wave ring
    __shared__ float pl[BLOCK];

    const int tid = threadIdx.x;
    const int lane = tid & 63;
    const int la = lane & 15;
    const int lg = lane >> 4;
    const int w = tid >> 6;
    const int gid = blockIdx.x * WPB + w;

    char* xb0 = xs + w * 16384;
    char* xb1 = xb0 + 8192;

    const int ntiles = N >> 4;                 // 16 rows/tile (16 | N here)
    const int full = ntiles / TOTAL_WAVES;     // uniform iterations (6)
    const int rem = ntiles - full * TOTAL_WAVES;

    const int srow = lane >> 5;                // row parity within 1KB chunk
    const int sslot = lane & 31;               // 16B slot within row

    // Stage one 16-row tile via DMA; source slot pre-swizzled (rule #21) to
    // match the read-side XOR. Phantom tiles clamp to last valid (L2-served).
    auto stage = [&](int t, char* dst) {
        int tt = t < ntiles ? t : ntiles - 1;
#pragma unroll
        for (int c = 0; c < 8; ++c) {
            int row = c * 2 + srow;
            int grow = tt * 16 + row;
            grow = grow < N ? grow : N - 1;
            int slot = sslot ^ (row & 7);
            gload16(X + (size_t)grow * D_DIM + slot * 4, dst + c * 1024);
        }
    };

    // ---- Prologue: 4 (m2) + 16 (B) + 8 (DMA tile0) = 28 VMEM outstanding ----
    float m2r[4];
    {
        const float* mp = m2g + la;
        LOADF(m2r[0], mp, 0);
        LOADF(m2r[1], mp, 64);
        LOADF(m2r[2], mp, 128);
        LOADF(m2r[3], mp, 192);
    }
    B8 bfr[4][4];   // [cb][kk], reused across all tiles of this wave
    {
        const int4* bp = muB4 + la * 16 + lg;
        LOADX4(bfr[0][0].i, bp, 0);  LOADX4(bfr[0][1].i, bp, 64);
        LOADX4(bfr[0][2].i, bp, 128); LOADX4(bfr[0][3].i, bp, 192);
        const int4* bp1 = bp + 256;
        LOADX4(bfr[1][0].i, bp1, 0);  LOADX4(bfr[1][1].i, bp1, 64);
        LOADX4(bfr[1][2].i, bp1, 128); LOADX4(bfr[1][3].i, bp1, 192);
        const int4* bp2 = bp + 512;
        LOADX4(bfr[2][0].i, bp2, 0);  LOADX4(bfr[2][1].i, bp2, 64);
        LOADX4(bfr[2][2].i, bp2, 128); LOADX4(bfr[2][3].i, bp2, 192);
        const int4* bp3 = bp + 768;
        LOADX4(bfr[3][0].i, bp3, 0);  LOADX4(bfr[3][1].i, bp3, 64);
        LOADX4(bfr[3][2].i, bp3, 128); LOADX4(bfr[3][3].i, bp3, 192);
    }
    stage(gid, xb0);
    __builtin_amdgcn_sched_barrier(0);

    float partial = 0.f;

    // ---- Steady loop. Outstanding at each WAITVM(24): DMA(t)[8 oldest] +
    // r(t)[16] + DMA(t+1)[8]  (k=0: prologue's 28 + 24 = 52; drains 28). ----
    for (int k = 0; k < full; ++k) {
        const int tk = k * TOTAL_WAVES + gid;
        float rv[4][4];
        const float* rp = r + ((size_t)tk * 16 + lg * 4) * M_CLUSTERS + la;
        load_rv(rp, rv);                               // +16
        stage(tk + TOTAL_WAVES, (k & 1) ? xb0 : xb1);  // +8 into other buffer
        WAITVM(24);                                    // drain DMA(t) (+prologue)
        const char* cur = (k & 1) ? xb1 : xb0;
        partial += compute_tile<8>(cur, la, lg, bfr, m2r, rv);
    }

    // ---- Peeled remainder (wave-uniform predicate) ----
    if (gid < rem) {
        const int tk = full * TOTAL_WAVES + gid;
        float rv[4][4];
        const float* rp = r + ((size_t)tk * 16 + lg * 4) * M_CLUSTERS + la;
        load_rv(rp, rv);   // outstanding: DMA(t)[8] + r[16]
        WAITVM(16);        // drain DMA(t)
        const char* cur = (full & 1) ? xb1 : xb0;
        partial += compute_tile<0>(cur, la, lg, bfr, m2r, rv);
    }

    // ---- Block reduce (single barrier; drains any dangling phantom DMA) ----
    pl[tid] = partial;
    __syncthreads();
    if (tid < 64) {
        float s = 0.f;
#pragma unroll
        for (int j = 0; j < WPB; ++j) s += pl[j * 64 + tid];
#pragma unroll
        for (int off = 32; off > 0; off >>= 1)
            s += __shfl_down(s, off, 64);
        if (tid == 0) partials[blockIdx.x] = s;
    }
}

// Deterministic fixed-order final reduction.
__global__ void iso_reduce(const float* __restrict__ partials, int nblocks,
                           float* __restrict__ out, float invN) {
    float s = 0.f;
    for (int i = threadIdx.x; i < nblocks; i += RBLOCK) s += partials[i];
#pragma unroll
    for (int off = 32; off > 0; off >>= 1)
        s += __shfl_down(s, off, 64);
    __shared__ float wsum[RBLOCK / 64];
    const int lane = threadIdx.x & 63;
    const int wid = threadIdx.x >> 6;
    if (lane == 0) wsum[wid] = s;
    __syncthreads();
    if (threadIdx.x == 0)
        out[0] = (wsum[0] + wsum[1] + wsum[2] + wsum[3]) * invN;
}

extern "C" void kernel_launch(void* const* d_in, const int* in_sizes, int n_in,
                              void* d_out, int out_size, void* d_ws, size_t ws_size,
                              hipStream_t stream) {
    const float* X = (const float*)d_in[0];    // [N,128]
    const float* r = (const float*)d_in[1];    // [N,64]
    const float* mus = (const float*)d_in[2];  // [64,128]
    const int N = in_sizes[0] / D_DIM;

    // ws: muB4 (1024 int4 = 16KB) | m2 (64 f32) | partials (GRID f32)
    int4* muB4 = (int4*)d_ws;
    float* m2 = (float*)((char*)d_ws + 16384);
    float* partials = m2 + M_CLUSTERS;

    hipLaunchKernelGGL(iso_prep, dim3(4), dim3(256), 0, stream,
                       (const float4*)mus, muB4, m2);
    hipLaunchKernelGGL(iso_main, dim3(GRID), dim3(BLOCK), 0, stream,
                       X, r, muB4, m2, partials, N);
    hipLaunchKernelGGL(iso_reduce, dim3(1), dim3(RBLOCK), 0, stream,
                       partials, GRID, (float*)d_out, 1.0f / (float)N);
}